// Round 3
// baseline (858.984 us; speedup 1.0000x reference)
//
#include <hip/hip_runtime.h>

#define N_NODES 4096
#define M_EDGES 4096
#define NNZ_K   262144
#define NCH     4
#define DIM     128
#define KDIM    512               // NCH*DIM
#define NM      (N_NODES * M_EDGES)
#define NUM_ADD 26214             // max(1, int(0.1*NNZ))
#define NCB     2048              // coarse bins over [-1, 1]
#define NFB     32768             // fine fp64 bins over the band
#define CAP     262144

// ---- workspace layout (byte offsets) ----
#define EXD_OFF   0ull                 // double[M*D]        4 MB
#define AFC_OFF   4194304ull           // bf16[N*512]        4 MB
#define BFC_OFF   8388608ull           // bf16[M*512]        4 MB
#define BKT_OFF   12582912ull          // int[NNZ]           1 MB
#define CVAL_OFF  13631488ull          // double[CAP]        2 MB
#define CIDX_OFF  15728640ull          // int[CAP]           1 MB
#define CNT_OFF   16777216ull          // int[4096]   (zeroed region starts here)
#define OFFS_OFF  16793600ull          // int[4097]
#define CUR_OFF   16810240ull          // int[4096]
#define HIST_OFF  16826624ull          // int[NCB]
#define FHIST_OFF 16834816ull          // int[NFB]  128 KB
#define SCL_OFF   16965888ull          // int[16] {bstar,-,ncand,-,fstar,G1f}
#define ZERO_BYTES (16965952ull - CNT_OFF)

typedef short bf16x8 __attribute__((ext_vector_type(8)));
typedef float f32x4  __attribute__((ext_vector_type(4)));

__device__ __forceinline__ int bin_c(float s) {
    int b = (int)floorf((s + 1.0f) * 1024.0f);
    return min(max(b, 0), NCB - 1);
}

// fine fp64 binning over [L(b*-12), L(b*-12)+28h); identical expression everywhere
__device__ __forceinline__ int fbin_of(double v, int bstar) {
    double lo = (double)(bstar - 12) * (2.0 / 2048.0) - 1.0;
    double wd = (28.0 * (2.0 / 2048.0)) / (double)NFB;
    int f = (int)floor((v - lo) / wd);
    return min(max(f, 0), NFB - 1);
}

__device__ __forceinline__ float st_mask(float p, float e) {
    float logit = logf(e) - logf(1.0f - e) + logf(p + 1e-8f) - logf(1.0f - p + 1e-8f);
    float soft  = 1.0f / (1.0f + expf(-2.0f * logit));   // sigmoid(logit/TEMP), TEMP=0.5
    float hard  = (soft > 0.5f) ? 1.0f : 0.0f;
    return (hard - soft) + soft;
}

__device__ __forceinline__ unsigned short to_bf16_rtne(float f) {
    unsigned int b = __float_as_uint(f);
    b += 0x7FFFu + ((b >> 16) & 1u);
    return (unsigned short)(b >> 16);
}

// ---- 1. per-edge counts ----
__global__ void k_count(const int* __restrict__ E, int* __restrict__ cnt) {
    int k = blockIdx.x * 256 + threadIdx.x;
    if (k < NNZ_K) atomicAdd(&cnt[E[k]], 1);
}

// ---- 2. exclusive scan over 4096 counts ----
__global__ __launch_bounds__(256) void k_scan(const int* __restrict__ cnt, int* __restrict__ offs) {
    __shared__ int part[256];
    int t = threadIdx.x;
    int loc[16]; int s = 0;
    for (int j = 0; j < 16; ++j) { loc[j] = cnt[t * 16 + j]; s += loc[j]; }
    part[t] = s;
    __syncthreads();
    if (t == 0) { int acc = 0; for (int i = 0; i < 256; ++i) { int v = part[i]; part[i] = acc; acc += v; } }
    __syncthreads();
    int acc = part[t];
    for (int j = 0; j < 16; ++j) { offs[t * 16 + j] = acc; acc += loc[j]; }
    if (t == 255) offs[4096] = acc;
}

// ---- 3. bucket fill ----
__global__ void k_fill(const int* __restrict__ E, const int* __restrict__ offs,
                       int* __restrict__ cur, int* __restrict__ bkt) {
    int k = blockIdx.x * 256 + threadIdx.x;
    if (k < NNZ_K) {
        int e = E[k];
        int pos = atomicAdd(&cur[e], 1);
        bkt[offs[e] + pos] = k;
    }
}

// ---- 4. deterministic scatter-mean (fp64) ----
__global__ __launch_bounds__(128) void k_edge_mean(
        const int* __restrict__ Vv, const int* __restrict__ cnt,
        const int* __restrict__ offs, const int* __restrict__ bkt,
        const float* __restrict__ X, double* __restrict__ eXd) {
    __shared__ int sk[1024];
    __shared__ int sv[1024];
    int m = blockIdx.x;
    int c = cnt[m]; if (c > 1024) c = 1024;
    int off = offs[m];
    for (int t = threadIdx.x; t < c; t += 128) sk[t] = bkt[off + t];
    __syncthreads();
    for (int t = threadIdx.x; t < c; t += 128) {   // rank sort (keys distinct)
        int key = sk[t]; int r = 0;
        for (int j = 0; j < c; ++j) r += (sk[j] < key);
        sv[r] = Vv[key];
    }
    __syncthreads();
    int d = threadIdx.x;
    double s = 0.0;
    for (int j = 0; j < c; ++j) s += (double)X[sv[j] * DIM + d];
    eXd[m * DIM + d] = s / (double)(c > 1 ? c : 1);
}

// ---- 5. per-channel L2-normalized features -> bf16 (fp64 internal) ----
template <typename T>
__global__ __launch_bounds__(128) void k_fc(const T* __restrict__ in,
                                            const float* __restrict__ w,
                                            unsigned short* __restrict__ out) {
    __shared__ double red[128];
    int n = blockIdx.x, d = threadIdx.x;
    double x = (double)in[n * DIM + d];
    for (int c = 0; c < NCH; ++c) {
        double v = x * (double)w[c * DIM + d];
        red[d] = v * v;
        __syncthreads();
        for (int s = 64; s > 0; s >>= 1) { if (d < s) red[d] += red[d + s]; __syncthreads(); }
        double denom = fmax(sqrt(red[0]), 1e-12);
        __syncthreads();
        out[n * KDIM + c * DIM + d] = to_bf16_rtne((float)(v / denom));
    }
}

// ---- 6. bf16 MFMA screening GEMM: S~ = 0.25 * A(4096,512) * B(4096,512)^T ----
__global__ __launch_bounds__(256) void k_gemm_mfma(const unsigned short* __restrict__ A,
                                                   const unsigned short* __restrict__ B,
                                                   float* __restrict__ S) {
    __shared__ short As[128][40];   // 80B rows: 5x16B -> conflict-light b128 reads
    __shared__ short Bs[128][40];
    int tid = threadIdx.x;
    int row0 = blockIdx.y * 128, col0 = blockIdx.x * 128;
    int w = tid >> 6, l = tid & 63;
    int wr = (w >> 1) * 64, wc = (w & 1) * 64;
    f32x4 acc[4][4] = {};
    const unsigned short* src = (tid < 128) ? (A + (size_t)(row0 + tid) * KDIM)
                                            : (B + (size_t)(col0 + (tid - 128)) * KDIM);
    short* dst = (tid < 128) ? &As[tid][0] : &Bs[tid - 128][0];
    for (int k0 = 0; k0 < KDIM; k0 += 32) {
        uint4 d0 = *(const uint4*)(src + k0);
        uint4 d1 = *(const uint4*)(src + k0 + 8);
        uint4 d2 = *(const uint4*)(src + k0 + 16);
        uint4 d3 = *(const uint4*)(src + k0 + 24);
        __syncthreads();
        *(uint4*)(dst + 0)  = d0;
        *(uint4*)(dst + 8)  = d1;
        *(uint4*)(dst + 16) = d2;
        *(uint4*)(dst + 24) = d3;
        __syncthreads();
        int kq = (l >> 4) * 8;
        bf16x8 af[4], bfr[4];
        #pragma unroll
        for (int m = 0; m < 4; ++m) af[m] = *(const bf16x8*)&As[wr + m * 16 + (l & 15)][kq];
        #pragma unroll
        for (int n = 0; n < 4; ++n) bfr[n] = *(const bf16x8*)&Bs[wc + n * 16 + (l & 15)][kq];
        #pragma unroll
        for (int m = 0; m < 4; ++m)
            #pragma unroll
            for (int n = 0; n < 4; ++n)
                acc[m][n] = __builtin_amdgcn_mfma_f32_16x16x32_bf16(af[m], bfr[n], acc[m][n], 0, 0, 0);
    }
    // C/D layout: col = lane&15, row = (lane>>4)*4 + j  [verified m89]
    #pragma unroll
    for (int m = 0; m < 4; ++m) {
        int r = row0 + wr + m * 16 + (l >> 4) * 4;
        #pragma unroll
        for (int n = 0; n < 4; ++n) {
            int c = col0 + wc + n * 16 + (l & 15);
            #pragma unroll
            for (int j = 0; j < 4; ++j)
                S[(size_t)(r + j) * M_EDGES + c] = 0.25f * acc[m][n][j];
        }
    }
}

// ---- 7. mask existing incidences ----
__global__ void k_mask(const int* __restrict__ Vv, const int* __restrict__ E, float* __restrict__ S) {
    int k = blockIdx.x * 256 + threadIdx.x;
    if (k < NNZ_K) S[(size_t)Vv[k] * M_EDGES + E[k]] = -1e30f;
}

// ---- 8. coarse histogram, LDS-privatized ----
__global__ __launch_bounds__(256) void k_hist_coarse(const float4* __restrict__ S4,
                                                     int* __restrict__ hist) {
    __shared__ int h[NCB];
    for (int i = threadIdx.x; i < NCB; i += 256) h[i] = 0;
    __syncthreads();
    int stride = gridDim.x * 256;
    for (int i = blockIdx.x * 256 + threadIdx.x; i < NM / 4; i += stride) {
        float4 v = S4[i];
        float sv[4] = {v.x, v.y, v.z, v.w};
        #pragma unroll
        for (int c = 0; c < 4; ++c)
            if (sv[c] > -2.0f) atomicAdd(&h[bin_c(sv[c])], 1);
    }
    __syncthreads();
    for (int i = threadIdx.x; i < NCB; i += 256)
        if (h[i]) atomicAdd(&hist[i], h[i]);
}

// ---- 9. find cutoff bin b* ----
__global__ __launch_bounds__(256) void k_findcut(const int* __restrict__ hist, int* __restrict__ scl) {
    __shared__ int part[256];
    int t = threadIdx.x;
    int loc[8]; int s = 0;
    for (int j = 0; j < 8; ++j) { loc[j] = hist[t * 8 + j]; s += loc[j]; }
    part[t] = s;
    __syncthreads();
    if (t == 0) { int acc = 0; for (int i = 255; i >= 0; --i) { int v = part[i]; part[i] = acc; acc += v; } }
    __syncthreads();
    int run = part[t];
    for (int j = 7; j >= 0; --j) {
        int h = loc[j];
        run += h;
        if (run >= NUM_ADD && run - h < NUM_ADD) scl[0] = t * 8 + j;
    }
}

// ---- 10. fused elementwise output + full-band candidate collection ----
// band: all valid entries with coarse bin >= b*-11 (covers 2*delta_bf16 + slack)
__global__ __launch_bounds__(256) void k_final(
        float* __restrict__ S, const float* __restrict__ H,
        const float* __restrict__ prob, const float* __restrict__ eps,
        int* __restrict__ scl, int* __restrict__ cidx) {
    size_t i = (size_t)blockIdx.x * 256 + threadIdx.x;   // over NM/4
    int blo = scl[0] - 11;
    float4 s = ((const float4*)S)[i];
    float4 h = ((const float4*)H)[i];
    float4 p = ((const float4*)prob)[i];
    float4 e = ((const float4*)eps)[i];
    float sv[4] = {s.x, s.y, s.z, s.w};
    float hv[4] = {h.x, h.y, h.z, h.w};
    float pv[4] = {p.x, p.y, p.z, p.w};
    float ev[4] = {e.x, e.y, e.z, e.w};
    float ov[4];
    #pragma unroll
    for (int c = 0; c < 4; ++c) {
        float sc = sv[c];
        if (sc > -2.0f && bin_c(sc) >= blo) {
            int slot = atomicAdd(&scl[2], 1);
            if (slot < CAP) cidx[slot] = (int)(i * 4 + c);
        }
        ov[c] = hv[c] * st_mask(pv[c], ev[c]);   // band members may be overwritten later
    }
    ((float4*)S)[i] = make_float4(ov[0], ov[1], ov[2], ov[3]);
}

// ---- 11. exact fp64 values for band candidates ----
__global__ __launch_bounds__(256) void k_exact(
        const int* __restrict__ scl, const int* __restrict__ cidx, double* __restrict__ cval,
        const float* __restrict__ X, const double* __restrict__ eXd, const float* __restrict__ cw) {
    int nc = scl[2]; if (nc > CAP) nc = CAP;
    for (int i = blockIdx.x * 256 + threadIdx.x; i < nc; i += 256 * 256) {
        int idx = cidx[i];
        int n = idx >> 12, m = idx & (M_EDGES - 1);
        double acc = 0.0;
        for (int c = 0; c < NCH; ++c) {
            double dn = 0.0, de = 0.0, dt = 0.0;
            for (int d = 0; d < DIM; ++d) {
                double w  = (double)cw[c * DIM + d];
                double xn = (double)X[n * DIM + d] * w;
                double xe = eXd[m * DIM + d] * w;
                dn += xn * xn; de += xe * xe; dt += xn * xe;
            }
            acc += dt / (fmax(sqrt(dn), 1e-12) * fmax(sqrt(de), 1e-12));
        }
        cval[i] = acc * 0.25;
    }
}

// ---- 12. fine fp64 histogram of band values ----
__global__ __launch_bounds__(256) void k_fhist(const int* __restrict__ scl,
                                               const int* __restrict__ cidx,
                                               const double* __restrict__ cval,
                                               int* __restrict__ fh) {
    int nc = scl[2]; if (nc > CAP) nc = CAP;
    int bstar = scl[0];
    for (int i = blockIdx.x * 256 + threadIdx.x; i < nc; i += 256 * 256)
        atomicAdd(&fh[fbin_of(cval[i], bstar)], 1);
}

// ---- 13. find fine cutoff f* and G1f = count(bin > f*) ----
__global__ __launch_bounds__(1024) void k_ffind(const int* __restrict__ fh, int* __restrict__ scl) {
    __shared__ int part[1024];
    int t = threadIdx.x;
    int loc[32]; int s = 0;
    for (int j = 0; j < 32; ++j) { loc[j] = fh[t * 32 + j]; s += loc[j]; }
    part[t] = s;
    __syncthreads();
    if (t == 0) { int acc = 0; for (int i = 1023; i >= 0; --i) { int v = part[i]; part[i] = acc; acc += v; } }
    __syncthreads();
    int run = part[t];
    for (int j = 31; j >= 0; --j) {
        int h = loc[j];
        run += h;
        if (run >= NUM_ADD && run - h < NUM_ADD) { scl[4] = t * 32 + j; scl[5] = run - h; }
    }
}

// ---- 14. write all candidates strictly above the fine cutoff bin ----
__global__ __launch_bounds__(256) void k_write(
        const int* __restrict__ scl, const int* __restrict__ cidx, const double* __restrict__ cval,
        const float* __restrict__ H, const float* __restrict__ prob, const float* __restrict__ eps,
        float* __restrict__ out) {
    int nc = scl[2]; if (nc > CAP) nc = CAP;
    int fs = scl[4], bstar = scl[0];
    for (int i = blockIdx.x * 256 + threadIdx.x; i < nc; i += 256 * 256) {
        if (fbin_of(cval[i], bstar) > fs) {
            int idx = cidx[i];
            out[idx] = (H[idx] + 1.0f) * st_mask(prob[idx], eps[idx]);
        }
    }
}

// ---- 15. exact tie-break inside the single ambiguous fine bin ----
__global__ __launch_bounds__(256) void k_tie(
        const int* __restrict__ scl, const int* __restrict__ cidx, const double* __restrict__ cval,
        const float* __restrict__ H, const float* __restrict__ prob, const float* __restrict__ eps,
        float* __restrict__ out) {
    __shared__ double mv[256];
    __shared__ int    mi[256];
    __shared__ int    cnt;
    int nc = scl[2]; if (nc > CAP) nc = CAP;
    int fs = scl[4], G1 = scl[5], bstar = scl[0];
    int t = threadIdx.x;
    if (t == 0) cnt = 0;
    __syncthreads();
    for (int i = t; i < nc; i += 256) {
        if (fbin_of(cval[i], bstar) == fs) {
            int s = atomicAdd(&cnt, 1);
            if (s < 256) { mv[s] = cval[i]; mi[s] = cidx[i]; }
        }
    }
    __syncthreads();
    int nm = min(cnt, 256);
    for (int k = t; k < nm; k += 256) {
        double v = mv[k]; int idx = mi[k];
        int rank = G1;
        for (int j = 0; j < nm; ++j)
            rank += (mv[j] > v || (mv[j] == v && mi[j] < idx)) ? 1 : 0;
        if (rank < NUM_ADD)
            out[idx] = (H[idx] + 1.0f) * st_mask(prob[idx], eps[idx]);
    }
}

extern "C" void kernel_launch(void* const* d_in, const int* in_sizes, int n_in,
                              void* d_out, int out_size, void* d_ws, size_t ws_size,
                              hipStream_t stream) {
    const float* X    = (const float*)d_in[0];
    const float* H    = (const float*)d_in[1];
    const int*   Vv   = (const int*)d_in[2];
    const int*   E    = (const int*)d_in[3];
    const float* prob = (const float*)d_in[4];
    const float* cw   = (const float*)d_in[5];
    const float* eps  = (const float*)d_in[6];
    float* out = (float*)d_out;
    char*  ws  = (char*)d_ws;

    double*         eXd  = (double*)(ws + EXD_OFF);
    unsigned short* Afc  = (unsigned short*)(ws + AFC_OFF);
    unsigned short* Bfc  = (unsigned short*)(ws + BFC_OFF);
    int*            bkt  = (int*)(ws + BKT_OFF);
    double*         cval = (double*)(ws + CVAL_OFF);
    int*            cidx = (int*)(ws + CIDX_OFF);
    int*            cnt  = (int*)(ws + CNT_OFF);
    int*            offs = (int*)(ws + OFFS_OFF);
    int*            cur  = (int*)(ws + CUR_OFF);
    int*            hist = (int*)(ws + HIST_OFF);
    int*            fh   = (int*)(ws + FHIST_OFF);
    int*            scl  = (int*)(ws + SCL_OFF);

    hipMemsetAsync(ws + CNT_OFF, 0, (size_t)ZERO_BYTES, stream);

    k_count<<<NNZ_K / 256, 256, 0, stream>>>(E, cnt);
    k_scan<<<1, 256, 0, stream>>>(cnt, offs);
    k_fill<<<NNZ_K / 256, 256, 0, stream>>>(E, offs, cur, bkt);
    k_edge_mean<<<M_EDGES, 128, 0, stream>>>(Vv, cnt, offs, bkt, X, eXd);
    k_fc<float><<<N_NODES, 128, 0, stream>>>(X, cw, Afc);
    k_fc<double><<<M_EDGES, 128, 0, stream>>>(eXd, cw, Bfc);
    dim3 gg(M_EDGES / 128, N_NODES / 128);
    k_gemm_mfma<<<gg, 256, 0, stream>>>(Afc, Bfc, out);
    k_mask<<<NNZ_K / 256, 256, 0, stream>>>(Vv, E, out);
    k_hist_coarse<<<512, 256, 0, stream>>>((const float4*)out, hist);
    k_findcut<<<1, 256, 0, stream>>>(hist, scl);
    k_final<<<NM / 4 / 256, 256, 0, stream>>>(out, H, prob, eps, scl, cidx);
    k_exact<<<256, 256, 0, stream>>>(scl, cidx, cval, X, eXd, cw);
    k_fhist<<<256, 256, 0, stream>>>(scl, cidx, cval, fh);
    k_ffind<<<1, 1024, 0, stream>>>(fh, scl);
    k_write<<<256, 256, 0, stream>>>(scl, cidx, cval, H, prob, eps, out);
    k_tie<<<1, 256, 0, stream>>>(scl, cidx, cval, H, prob, eps, out);
}

// Round 4
// 719.189 us; speedup vs baseline: 1.1944x; 1.1944x over previous
//
#include <hip/hip_runtime.h>

#define N_NODES 4096
#define M_EDGES 4096
#define NNZ_K   262144
#define NCH     4
#define DIM     128
#define KDIM    512               // NCH*DIM
#define NM      (N_NODES * M_EDGES)
#define NUM_ADD 26214             // max(1, int(0.1*NNZ))
#define NCB     2048              // coarse bins over [-1, 1]
#define NFB     32768             // fine fp64 bins over the band
#define CAP     262144
#define CAP2    65536

// ---- workspace layout (byte offsets) ----
#define EXD_OFF   0ull                 // double[M*D]        4 MB
#define AFC_OFF   4194304ull           // bf16[N*512]        4 MB
#define BFC_OFF   8388608ull           // bf16[M*512]        4 MB
#define BKT_OFF   12582912ull          // int[NNZ]           1 MB
#define CVAL_OFF  13631488ull          // double[CAP]        2 MB
#define CIDX_OFF  15728640ull          // int[CAP]           1 MB
#define CIDX2_OFF 16777216ull          // int[CAP2]          256 KB
#define CNT_OFF   17039360ull          // int[4096]  (zeroed region starts here)
#define OFFS_OFF  17055744ull          // int[4097]
#define CUR_OFF   17072132ull          // int[4096]
#define HIST_OFF  17088516ull          // int[NCB]
#define FHIST_OFF 17096708ull          // int[NFB] 128 KB
#define SCL_OFF   17227780ull          // int[16] {bstar,G1,ncand,ncert,fstar,G1f}
#define ZERO_BYTES (17227844ull - CNT_OFF)

typedef short bf16x8 __attribute__((ext_vector_type(8)));
typedef float f32x4  __attribute__((ext_vector_type(4)));

__device__ __forceinline__ int bin_c(float s) {
    int b = (int)floorf((s + 1.0f) * 1024.0f);
    return min(max(b, 0), NCB - 1);
}

// fine fp64 binning over [L(b*-12), L(b*-12)+28h); band [b*-11,b*+10] maps inside
__device__ __forceinline__ int fbin_of(double v, int bstar) {
    double lo = (double)(bstar - 12) * (2.0 / 2048.0) - 1.0;
    double wd = (28.0 * (2.0 / 2048.0)) / (double)NFB;
    int f = (int)floor((v - lo) / wd);
    return min(max(f, 0), NFB - 1);
}

// kept BIT-IDENTICAL to the passing rounds — do not algebraically simplify
__device__ __forceinline__ float st_mask(float p, float e) {
    float logit = logf(e) - logf(1.0f - e) + logf(p + 1e-8f) - logf(1.0f - p + 1e-8f);
    float soft  = 1.0f / (1.0f + expf(-2.0f * logit));   // sigmoid(logit/TEMP), TEMP=0.5
    float hard  = (soft > 0.5f) ? 1.0f : 0.0f;
    return (hard - soft) + soft;
}

__device__ __forceinline__ unsigned short to_bf16_rtne(float f) {
    unsigned int b = __float_as_uint(f);
    b += 0x7FFFu + ((b >> 16) & 1u);
    return (unsigned short)(b >> 16);
}

// ---- 1. per-edge counts ----
__global__ void k_count(const int* __restrict__ E, int* __restrict__ cnt) {
    int k = blockIdx.x * 256 + threadIdx.x;
    if (k < NNZ_K) atomicAdd(&cnt[E[k]], 1);
}

// ---- 2. exclusive scan over 4096 counts ----
__global__ __launch_bounds__(256) void k_scan(const int* __restrict__ cnt, int* __restrict__ offs) {
    __shared__ int part[256];
    int t = threadIdx.x;
    int loc[16]; int s = 0;
    for (int j = 0; j < 16; ++j) { loc[j] = cnt[t * 16 + j]; s += loc[j]; }
    part[t] = s;
    __syncthreads();
    if (t == 0) { int acc = 0; for (int i = 0; i < 256; ++i) { int v = part[i]; part[i] = acc; acc += v; } }
    __syncthreads();
    int acc = part[t];
    for (int j = 0; j < 16; ++j) { offs[t * 16 + j] = acc; acc += loc[j]; }
    if (t == 255) offs[4096] = acc;
}

// ---- 3. bucket fill ----
__global__ void k_fill(const int* __restrict__ E, const int* __restrict__ offs,
                       int* __restrict__ cur, int* __restrict__ bkt) {
    int k = blockIdx.x * 256 + threadIdx.x;
    if (k < NNZ_K) {
        int e = E[k];
        int pos = atomicAdd(&cur[e], 1);
        bkt[offs[e] + pos] = k;
    }
}

// ---- 4. deterministic scatter-mean (fp64) ----
__global__ __launch_bounds__(128) void k_edge_mean(
        const int* __restrict__ Vv, const int* __restrict__ cnt,
        const int* __restrict__ offs, const int* __restrict__ bkt,
        const float* __restrict__ X, double* __restrict__ eXd) {
    __shared__ int sk[1024];
    __shared__ int sv[1024];
    int m = blockIdx.x;
    int c = cnt[m]; if (c > 1024) c = 1024;
    int off = offs[m];
    for (int t = threadIdx.x; t < c; t += 128) sk[t] = bkt[off + t];
    __syncthreads();
    for (int t = threadIdx.x; t < c; t += 128) {   // rank sort (keys distinct)
        int key = sk[t]; int r = 0;
        for (int j = 0; j < c; ++j) r += (sk[j] < key);
        sv[r] = Vv[key];
    }
    __syncthreads();
    int d = threadIdx.x;
    double s = 0.0;
    for (int j = 0; j < c; ++j) s += (double)X[sv[j] * DIM + d];
    eXd[m * DIM + d] = s / (double)(c > 1 ? c : 1);
}

// ---- 5. per-channel L2-normalized features -> bf16 (fp64 internal) ----
template <typename T>
__global__ __launch_bounds__(128) void k_fc(const T* __restrict__ in,
                                            const float* __restrict__ w,
                                            unsigned short* __restrict__ out) {
    __shared__ double red[128];
    int n = blockIdx.x, d = threadIdx.x;
    double x = (double)in[n * DIM + d];
    for (int c = 0; c < NCH; ++c) {
        double v = x * (double)w[c * DIM + d];
        red[d] = v * v;
        __syncthreads();
        for (int s = 64; s > 0; s >>= 1) { if (d < s) red[d] += red[d + s]; __syncthreads(); }
        double denom = fmax(sqrt(red[0]), 1e-12);
        __syncthreads();
        out[n * KDIM + c * DIM + d] = to_bf16_rtne((float)(v / denom));
    }
}

// ---- 6. bf16 MFMA screening GEMM ----
__global__ __launch_bounds__(256) void k_gemm_mfma(const unsigned short* __restrict__ A,
                                                   const unsigned short* __restrict__ B,
                                                   float* __restrict__ S) {
    __shared__ short As[128][40];
    __shared__ short Bs[128][40];
    int tid = threadIdx.x;
    int row0 = blockIdx.y * 128, col0 = blockIdx.x * 128;
    int w = tid >> 6, l = tid & 63;
    int wr = (w >> 1) * 64, wc = (w & 1) * 64;
    f32x4 acc[4][4] = {};
    const unsigned short* src = (tid < 128) ? (A + (size_t)(row0 + tid) * KDIM)
                                            : (B + (size_t)(col0 + (tid - 128)) * KDIM);
    short* dst = (tid < 128) ? &As[tid][0] : &Bs[tid - 128][0];
    for (int k0 = 0; k0 < KDIM; k0 += 32) {
        uint4 d0 = *(const uint4*)(src + k0);
        uint4 d1 = *(const uint4*)(src + k0 + 8);
        uint4 d2 = *(const uint4*)(src + k0 + 16);
        uint4 d3 = *(const uint4*)(src + k0 + 24);
        __syncthreads();
        *(uint4*)(dst + 0)  = d0;
        *(uint4*)(dst + 8)  = d1;
        *(uint4*)(dst + 16) = d2;
        *(uint4*)(dst + 24) = d3;
        __syncthreads();
        int kq = (l >> 4) * 8;
        bf16x8 af[4], bfr[4];
        #pragma unroll
        for (int m = 0; m < 4; ++m) af[m] = *(const bf16x8*)&As[wr + m * 16 + (l & 15)][kq];
        #pragma unroll
        for (int n = 0; n < 4; ++n) bfr[n] = *(const bf16x8*)&Bs[wc + n * 16 + (l & 15)][kq];
        #pragma unroll
        for (int m = 0; m < 4; ++m)
            #pragma unroll
            for (int n = 0; n < 4; ++n)
                acc[m][n] = __builtin_amdgcn_mfma_f32_16x16x32_bf16(af[m], bfr[n], acc[m][n], 0, 0, 0);
    }
    #pragma unroll
    for (int m = 0; m < 4; ++m) {
        int r = row0 + wr + m * 16 + (l >> 4) * 4;
        #pragma unroll
        for (int n = 0; n < 4; ++n) {
            int c = col0 + wc + n * 16 + (l & 15);
            #pragma unroll
            for (int j = 0; j < 4; ++j)
                S[(size_t)(r + j) * M_EDGES + c] = 0.25f * acc[m][n][j];
        }
    }
}

// ---- 7. mask existing incidences ----
__global__ void k_mask(const int* __restrict__ Vv, const int* __restrict__ E, float* __restrict__ S) {
    int k = blockIdx.x * 256 + threadIdx.x;
    if (k < NNZ_K) S[(size_t)Vv[k] * M_EDGES + E[k]] = -1e30f;
}

// ---- 8. coarse histogram, LDS-privatized, scalar-expanded ----
__global__ __launch_bounds__(256) void k_hist_coarse(const float4* __restrict__ S4,
                                                     int* __restrict__ hist) {
    __shared__ int h[NCB];
    for (int i = threadIdx.x; i < NCB; i += 256) h[i] = 0;
    __syncthreads();
    int stride = gridDim.x * 256;
    for (int i = blockIdx.x * 256 + threadIdx.x; i < NM / 4; i += stride) {
        float4 v = S4[i];
        if (v.x > -2.0f) atomicAdd(&h[bin_c(v.x)], 1);
        if (v.y > -2.0f) atomicAdd(&h[bin_c(v.y)], 1);
        if (v.z > -2.0f) atomicAdd(&h[bin_c(v.z)], 1);
        if (v.w > -2.0f) atomicAdd(&h[bin_c(v.w)], 1);
    }
    __syncthreads();
    for (int i = threadIdx.x; i < NCB; i += 256)
        if (h[i]) atomicAdd(&hist[i], h[i]);
}

// ---- 9. find cutoff bin b*, then G1 = count(bin >= b*+11) ----
__global__ __launch_bounds__(256) void k_findcut(const int* __restrict__ hist, int* __restrict__ scl) {
    __shared__ int part[256];
    __shared__ int sb;
    int t = threadIdx.x;
    int loc[8]; int s = 0;
    for (int j = 0; j < 8; ++j) { loc[j] = hist[t * 8 + j]; s += loc[j]; }
    part[t] = s;
    __syncthreads();
    if (t == 0) { int acc = 0; for (int i = 255; i >= 0; --i) { int v = part[i]; part[i] = acc; acc += v; } }
    __syncthreads();
    int run = part[t];
    for (int j = 7; j >= 0; --j) {
        int h = loc[j];
        run += h;
        if (run >= NUM_ADD && run - h < NUM_ADD) { scl[0] = t * 8 + j; sb = t * 8 + j; }
    }
    __syncthreads();
    int bstar = sb;
    int g = 0;
    for (int i = bstar + 11 + t; i < NCB; i += 256) g += hist[i];
    part[t] = g;
    __syncthreads();
    for (int st2 = 128; st2 > 0; st2 >>= 1) { if (t < st2) part[t] += part[t + st2]; __syncthreads(); }
    if (t == 0) scl[1] = part[0];    // G1: certainly-selected (exact integer count)
}

// ---- 10. collect: certain (bin>=b*+11) -> cidx2, band [b*-11,b*+10] -> cidx ----
__global__ __launch_bounds__(256) void k_collect(const float4* __restrict__ S4,
        int* __restrict__ scl, int* __restrict__ cidx, int* __restrict__ cidx2) {
    size_t base = ((size_t)blockIdx.x * 256 + threadIdx.x) * 2;
    int bstar = scl[0];
    #pragma unroll
    for (int q = 0; q < 2; ++q) {
        size_t i = base + q;
        float4 v = S4[i];
        float sc; int c;
        #define COLLECT1(comp, cc)                                             \
            sc = comp; c = cc;                                                 \
            if (sc > -2.0f) {                                                  \
                int b = bin_c(sc);                                             \
                if (b >= bstar + 11) {                                         \
                    int slot = atomicAdd(&scl[3], 1);                          \
                    if (slot < CAP2) cidx2[slot] = (int)(i * 4 + c);           \
                } else if (b >= bstar - 11) {                                  \
                    int slot = atomicAdd(&scl[2], 1);                          \
                    if (slot < CAP) cidx[slot] = (int)(i * 4 + c);             \
                }                                                              \
            }
        COLLECT1(v.x, 0) COLLECT1(v.y, 1) COLLECT1(v.z, 2) COLLECT1(v.w, 3)
        #undef COLLECT1
    }
}

// ---- 11. pure-stream output: out = H * st_mask  (no S, no atomics) ----
__global__ __launch_bounds__(256) void k_out(const float4* __restrict__ H4,
        const float4* __restrict__ p4, const float4* __restrict__ e4,
        float4* __restrict__ o4) {
    size_t base = ((size_t)blockIdx.x * 256 + threadIdx.x) * 2;
    float4 h0 = H4[base],     h1 = H4[base + 1];
    float4 p0 = p4[base],     p1 = p4[base + 1];
    float4 e0 = e4[base],     e1 = e4[base + 1];
    float4 o0, o1;
    o0.x = h0.x * st_mask(p0.x, e0.x);
    o0.y = h0.y * st_mask(p0.y, e0.y);
    o0.z = h0.z * st_mask(p0.z, e0.z);
    o0.w = h0.w * st_mask(p0.w, e0.w);
    o1.x = h1.x * st_mask(p1.x, e1.x);
    o1.y = h1.y * st_mask(p1.y, e1.y);
    o1.z = h1.z * st_mask(p1.z, e1.z);
    o1.w = h1.w * st_mask(p1.w, e1.w);
    o4[base] = o0;
    o4[base + 1] = o1;
}

// ---- 12. scatter-write certain entries: out = (H+1)*mask ----
__global__ __launch_bounds__(256) void k_selc(const int* __restrict__ scl,
        const int* __restrict__ cidx2, const float* __restrict__ H,
        const float* __restrict__ prob, const float* __restrict__ eps,
        float* __restrict__ out) {
    int n = scl[3]; if (n > CAP2) n = CAP2;
    for (int i = blockIdx.x * 256 + threadIdx.x; i < n; i += 256 * 128) {
        int idx = cidx2[i];
        out[idx] = (H[idx] + 1.0f) * st_mask(prob[idx], eps[idx]);
    }
}

// ---- 13. exact fp64 values for band candidates ----
__global__ __launch_bounds__(256) void k_exact(
        const int* __restrict__ scl, const int* __restrict__ cidx, double* __restrict__ cval,
        const float* __restrict__ X, const double* __restrict__ eXd, const float* __restrict__ cw) {
    int nc = scl[2]; if (nc > CAP) nc = CAP;
    for (int i = blockIdx.x * 256 + threadIdx.x; i < nc; i += 256 * 256) {
        int idx = cidx[i];
        int n = idx >> 12, m = idx & (M_EDGES - 1);
        double acc = 0.0;
        for (int c = 0; c < NCH; ++c) {
            double dn = 0.0, de = 0.0, dt = 0.0;
            for (int d = 0; d < DIM; ++d) {
                double w  = (double)cw[c * DIM + d];
                double xn = (double)X[n * DIM + d] * w;
                double xe = eXd[m * DIM + d] * w;
                dn += xn * xn; de += xe * xe; dt += xn * xe;
            }
            acc += dt / (fmax(sqrt(dn), 1e-12) * fmax(sqrt(de), 1e-12));
        }
        cval[i] = acc * 0.25;
    }
}

// ---- 14. fine fp64 histogram of band values ----
__global__ __launch_bounds__(256) void k_fhist(const int* __restrict__ scl,
                                               const int* __restrict__ cidx,
                                               const double* __restrict__ cval,
                                               int* __restrict__ fh) {
    int nc = scl[2]; if (nc > CAP) nc = CAP;
    int bstar = scl[0];
    for (int i = blockIdx.x * 256 + threadIdx.x; i < nc; i += 256 * 256)
        atomicAdd(&fh[fbin_of(cval[i], bstar)], 1);
}

// ---- 15. find fine cutoff f* for target T = NUM_ADD - G1 ----
__global__ __launch_bounds__(1024) void k_ffind(const int* __restrict__ fh, int* __restrict__ scl) {
    __shared__ int part[1024];
    int T = NUM_ADD - scl[1];            // >= 1 by construction of b*
    int t = threadIdx.x;
    int loc[32]; int s = 0;
    for (int j = 0; j < 32; ++j) { loc[j] = fh[t * 32 + j]; s += loc[j]; }
    part[t] = s;
    __syncthreads();
    if (t == 0) { int acc = 0; for (int i = 1023; i >= 0; --i) { int v = part[i]; part[i] = acc; acc += v; } }
    __syncthreads();
    int run = part[t];
    for (int j = 31; j >= 0; --j) {
        int h = loc[j];
        run += h;
        if (run >= T && run - h < T) { scl[4] = t * 32 + j; scl[5] = run - h; }
    }
}

// ---- 16. write band candidates strictly above the fine cutoff bin ----
__global__ __launch_bounds__(256) void k_write(
        const int* __restrict__ scl, const int* __restrict__ cidx, const double* __restrict__ cval,
        const float* __restrict__ H, const float* __restrict__ prob, const float* __restrict__ eps,
        float* __restrict__ out) {
    int nc = scl[2]; if (nc > CAP) nc = CAP;
    int fs = scl[4], bstar = scl[0];
    for (int i = blockIdx.x * 256 + threadIdx.x; i < nc; i += 256 * 256) {
        if (fbin_of(cval[i], bstar) > fs) {
            int idx = cidx[i];
            out[idx] = (H[idx] + 1.0f) * st_mask(prob[idx], eps[idx]);
        }
    }
}

// ---- 17. exact tie-break inside the single ambiguous fine bin ----
__global__ __launch_bounds__(256) void k_tie(
        const int* __restrict__ scl, const int* __restrict__ cidx, const double* __restrict__ cval,
        const float* __restrict__ H, const float* __restrict__ prob, const float* __restrict__ eps,
        float* __restrict__ out) {
    __shared__ double mv[256];
    __shared__ int    mi[256];
    __shared__ int    cnt;
    int nc = scl[2]; if (nc > CAP) nc = CAP;
    int T = NUM_ADD - scl[1];
    int fs = scl[4], G1f = scl[5], bstar = scl[0];
    int t = threadIdx.x;
    if (t == 0) cnt = 0;
    __syncthreads();
    for (int i = t; i < nc; i += 256) {
        if (fbin_of(cval[i], bstar) == fs) {
            int s = atomicAdd(&cnt, 1);
            if (s < 256) { mv[s] = cval[i]; mi[s] = cidx[i]; }
        }
    }
    __syncthreads();
    int nm = min(cnt, 256);
    for (int k = t; k < nm; k += 256) {
        double v = mv[k]; int idx = mi[k];
        int rank = G1f;
        for (int j = 0; j < nm; ++j)
            rank += (mv[j] > v || (mv[j] == v && mi[j] < idx)) ? 1 : 0;
        if (rank < T)
            out[idx] = (H[idx] + 1.0f) * st_mask(prob[idx], eps[idx]);
    }
}

extern "C" void kernel_launch(void* const* d_in, const int* in_sizes, int n_in,
                              void* d_out, int out_size, void* d_ws, size_t ws_size,
                              hipStream_t stream) {
    const float* X    = (const float*)d_in[0];
    const float* H    = (const float*)d_in[1];
    const int*   Vv   = (const int*)d_in[2];
    const int*   E    = (const int*)d_in[3];
    const float* prob = (const float*)d_in[4];
    const float* cw   = (const float*)d_in[5];
    const float* eps  = (const float*)d_in[6];
    float* out = (float*)d_out;
    char*  ws  = (char*)d_ws;

    double*         eXd   = (double*)(ws + EXD_OFF);
    unsigned short* Afc   = (unsigned short*)(ws + AFC_OFF);
    unsigned short* Bfc   = (unsigned short*)(ws + BFC_OFF);
    int*            bkt   = (int*)(ws + BKT_OFF);
    double*         cval  = (double*)(ws + CVAL_OFF);
    int*            cidx  = (int*)(ws + CIDX_OFF);
    int*            cidx2 = (int*)(ws + CIDX2_OFF);
    int*            cnt   = (int*)(ws + CNT_OFF);
    int*            offs  = (int*)(ws + OFFS_OFF);
    int*            cur   = (int*)(ws + CUR_OFF);
    int*            hist  = (int*)(ws + HIST_OFF);
    int*            fh    = (int*)(ws + FHIST_OFF);
    int*            scl   = (int*)(ws + SCL_OFF);

    hipMemsetAsync(ws + CNT_OFF, 0, (size_t)ZERO_BYTES, stream);

    k_count<<<NNZ_K / 256, 256, 0, stream>>>(E, cnt);
    k_scan<<<1, 256, 0, stream>>>(cnt, offs);
    k_fill<<<NNZ_K / 256, 256, 0, stream>>>(E, offs, cur, bkt);
    k_edge_mean<<<M_EDGES, 128, 0, stream>>>(Vv, cnt, offs, bkt, X, eXd);
    k_fc<float><<<N_NODES, 128, 0, stream>>>(X, cw, Afc);
    k_fc<double><<<M_EDGES, 128, 0, stream>>>(eXd, cw, Bfc);
    dim3 gg(M_EDGES / 128, N_NODES / 128);
    k_gemm_mfma<<<gg, 256, 0, stream>>>(Afc, Bfc, out);
    k_mask<<<NNZ_K / 256, 256, 0, stream>>>(Vv, E, out);
    k_hist_coarse<<<1024, 256, 0, stream>>>((const float4*)out, hist);
    k_findcut<<<1, 256, 0, stream>>>(hist, scl);
    k_collect<<<NM / 8 / 256, 256, 0, stream>>>((const float4*)out, scl, cidx, cidx2);
    k_out<<<NM / 8 / 256, 256, 0, stream>>>((const float4*)H, (const float4*)prob,
                                            (const float4*)eps, (float4*)out);
    k_selc<<<128, 256, 0, stream>>>(scl, cidx2, H, prob, eps, out);
    k_exact<<<256, 256, 0, stream>>>(scl, cidx, cval, X, eXd, cw);
    k_fhist<<<256, 256, 0, stream>>>(scl, cidx, cval, fh);
    k_ffind<<<1, 1024, 0, stream>>>(fh, scl);
    k_write<<<256, 256, 0, stream>>>(scl, cidx, cval, H, prob, eps, out);
    k_tie<<<1, 256, 0, stream>>>(scl, cidx, cval, H, prob, eps, out);
}

// Round 5
// 340.287 us; speedup vs baseline: 2.5243x; 2.1135x over previous
//
#include <hip/hip_runtime.h>

#define N_NODES 4096
#define M_EDGES 4096
#define NNZ_K   262144
#define NCH     4
#define DIM     128
#define KDIM    512               // NCH*DIM
#define NM      (N_NODES * M_EDGES)
#define NUM_ADD 26214             // max(1, int(0.1*NNZ))
#define NCB     2048              // coarse bins over [-1, 1]
#define NFB     32768             // fine fp64 bins over the band
#define CAP     262144
#define CAP2    65536

// ---- workspace layout (byte offsets) ----
#define EXD_OFF   0ull                 // double[M*D]        4 MB
#define AFC_OFF   4194304ull           // bf16[N*512]        4 MB
#define BFC_OFF   8388608ull           // bf16[M*512]        4 MB
#define BKT_OFF   12582912ull          // int[NNZ]           1 MB
#define CVAL_OFF  13631488ull          // double[CAP]        2 MB
#define CIDX_OFF  15728640ull          // int[CAP]           1 MB
#define CIDX2_OFF 16777216ull          // int[CAP2]          256 KB
#define CNT_OFF   17039360ull          // int[4096]  (zeroed region starts here)
#define OFFS_OFF  17055744ull          // int[4097]
#define CUR_OFF   17072132ull          // int[4096]
#define HIST_OFF  17088516ull          // int[NCB]
#define FHIST_OFF 17096708ull          // int[NFB] 128 KB
#define SCL_OFF   17227780ull          // int[16] {bstar,G1,ncand,ncert,fstar,G1f}
#define ZERO_BYTES (17227844ull - CNT_OFF)

typedef short bf16x8 __attribute__((ext_vector_type(8)));
typedef float f32x4  __attribute__((ext_vector_type(4)));

__device__ __forceinline__ int bin_c(float s) {
    int b = (int)floorf((s + 1.0f) * 1024.0f);
    return min(max(b, 0), NCB - 1);
}

// fine fp64 binning over [L(b*-12), L(b*-12)+28h); band [b*-11,b*+10] maps inside
__device__ __forceinline__ int fbin_of(double v, int bstar) {
    double lo = (double)(bstar - 12) * (2.0 / 2048.0) - 1.0;
    double wd = (28.0 * (2.0 / 2048.0)) / (double)NFB;
    int f = (int)floor((v - lo) / wd);
    return min(max(f, 0), NFB - 1);
}

// kept BIT-IDENTICAL to the passing rounds — do not algebraically simplify
__device__ __forceinline__ float st_mask(float p, float e) {
    float logit = logf(e) - logf(1.0f - e) + logf(p + 1e-8f) - logf(1.0f - p + 1e-8f);
    float soft  = 1.0f / (1.0f + expf(-2.0f * logit));   // sigmoid(logit/TEMP), TEMP=0.5
    float hard  = (soft > 0.5f) ? 1.0f : 0.0f;
    return (hard - soft) + soft;
}

__device__ __forceinline__ unsigned short to_bf16_rtne(float f) {
    unsigned int b = __float_as_uint(f);
    b += 0x7FFFu + ((b >> 16) & 1u);
    return (unsigned short)(b >> 16);
}

// ---- 1. per-edge counts ----
__global__ void k_count(const int* __restrict__ E, int* __restrict__ cnt) {
    int k = blockIdx.x * 256 + threadIdx.x;
    if (k < NNZ_K) atomicAdd(&cnt[E[k]], 1);
}

// ---- 2. exclusive scan over 4096 counts ----
__global__ __launch_bounds__(256) void k_scan(const int* __restrict__ cnt, int* __restrict__ offs) {
    __shared__ int part[256];
    int t = threadIdx.x;
    int loc[16]; int s = 0;
    for (int j = 0; j < 16; ++j) { loc[j] = cnt[t * 16 + j]; s += loc[j]; }
    part[t] = s;
    __syncthreads();
    if (t == 0) { int acc = 0; for (int i = 0; i < 256; ++i) { int v = part[i]; part[i] = acc; acc += v; } }
    __syncthreads();
    int acc = part[t];
    for (int j = 0; j < 16; ++j) { offs[t * 16 + j] = acc; acc += loc[j]; }
    if (t == 255) offs[4096] = acc;
}

// ---- 3. bucket fill ----
__global__ void k_fill(const int* __restrict__ E, const int* __restrict__ offs,
                       int* __restrict__ cur, int* __restrict__ bkt) {
    int k = blockIdx.x * 256 + threadIdx.x;
    if (k < NNZ_K) {
        int e = E[k];
        int pos = atomicAdd(&cur[e], 1);
        bkt[offs[e] + pos] = k;
    }
}

// ---- 4. deterministic scatter-mean (fp64) ----
__global__ __launch_bounds__(128) void k_edge_mean(
        const int* __restrict__ Vv, const int* __restrict__ cnt,
        const int* __restrict__ offs, const int* __restrict__ bkt,
        const float* __restrict__ X, double* __restrict__ eXd) {
    __shared__ int sk[1024];
    __shared__ int sv[1024];
    int m = blockIdx.x;
    int c = cnt[m]; if (c > 1024) c = 1024;
    int off = offs[m];
    for (int t = threadIdx.x; t < c; t += 128) sk[t] = bkt[off + t];
    __syncthreads();
    for (int t = threadIdx.x; t < c; t += 128) {   // rank sort (keys distinct)
        int key = sk[t]; int r = 0;
        for (int j = 0; j < c; ++j) r += (sk[j] < key);
        sv[r] = Vv[key];
    }
    __syncthreads();
    int d = threadIdx.x;
    double s = 0.0;
    for (int j = 0; j < c; ++j) s += (double)X[sv[j] * DIM + d];
    eXd[m * DIM + d] = s / (double)(c > 1 ? c : 1);
}

// ---- 5. per-channel L2-normalized features -> bf16 (fp64 internal) ----
template <typename T>
__global__ __launch_bounds__(128) void k_fc(const T* __restrict__ in,
                                            const float* __restrict__ w,
                                            unsigned short* __restrict__ out) {
    __shared__ double red[128];
    int n = blockIdx.x, d = threadIdx.x;
    double x = (double)in[n * DIM + d];
    for (int c = 0; c < NCH; ++c) {
        double v = x * (double)w[c * DIM + d];
        red[d] = v * v;
        __syncthreads();
        for (int s = 64; s > 0; s >>= 1) { if (d < s) red[d] += red[d + s]; __syncthreads(); }
        double denom = fmax(sqrt(red[0]), 1e-12);
        __syncthreads();
        out[n * KDIM + c * DIM + d] = to_bf16_rtne((float)(v / denom));
    }
}

// ---- 6. bf16 MFMA screening GEMM ----
__global__ __launch_bounds__(256) void k_gemm_mfma(const unsigned short* __restrict__ A,
                                                   const unsigned short* __restrict__ B,
                                                   float* __restrict__ S) {
    __shared__ short As[128][40];
    __shared__ short Bs[128][40];
    int tid = threadIdx.x;
    int row0 = blockIdx.y * 128, col0 = blockIdx.x * 128;
    int w = tid >> 6, l = tid & 63;
    int wr = (w >> 1) * 64, wc = (w & 1) * 64;
    f32x4 acc[4][4] = {};
    const unsigned short* src = (tid < 128) ? (A + (size_t)(row0 + tid) * KDIM)
                                            : (B + (size_t)(col0 + (tid - 128)) * KDIM);
    short* dst = (tid < 128) ? &As[tid][0] : &Bs[tid - 128][0];
    for (int k0 = 0; k0 < KDIM; k0 += 32) {
        uint4 d0 = *(const uint4*)(src + k0);
        uint4 d1 = *(const uint4*)(src + k0 + 8);
        uint4 d2 = *(const uint4*)(src + k0 + 16);
        uint4 d3 = *(const uint4*)(src + k0 + 24);
        __syncthreads();
        *(uint4*)(dst + 0)  = d0;
        *(uint4*)(dst + 8)  = d1;
        *(uint4*)(dst + 16) = d2;
        *(uint4*)(dst + 24) = d3;
        __syncthreads();
        int kq = (l >> 4) * 8;
        bf16x8 af[4], bfr[4];
        #pragma unroll
        for (int m = 0; m < 4; ++m) af[m] = *(const bf16x8*)&As[wr + m * 16 + (l & 15)][kq];
        #pragma unroll
        for (int n = 0; n < 4; ++n) bfr[n] = *(const bf16x8*)&Bs[wc + n * 16 + (l & 15)][kq];
        #pragma unroll
        for (int m = 0; m < 4; ++m)
            #pragma unroll
            for (int n = 0; n < 4; ++n)
                acc[m][n] = __builtin_amdgcn_mfma_f32_16x16x32_bf16(af[m], bfr[n], acc[m][n], 0, 0, 0);
    }
    #pragma unroll
    for (int m = 0; m < 4; ++m) {
        int r = row0 + wr + m * 16 + (l >> 4) * 4;
        #pragma unroll
        for (int n = 0; n < 4; ++n) {
            int c = col0 + wc + n * 16 + (l & 15);
            #pragma unroll
            for (int j = 0; j < 4; ++j)
                S[(size_t)(r + j) * M_EDGES + c] = 0.25f * acc[m][n][j];
        }
    }
}

// ---- 7. mask existing incidences ----
__global__ void k_mask(const int* __restrict__ Vv, const int* __restrict__ E, float* __restrict__ S) {
    int k = blockIdx.x * 256 + threadIdx.x;
    if (k < NNZ_K) S[(size_t)Vv[k] * M_EDGES + E[k]] = -1e30f;
}

// ---- 8. coarse histogram, LDS-privatized ----
__global__ __launch_bounds__(256) void k_hist_coarse(const float4* __restrict__ S4,
                                                     int* __restrict__ hist) {
    __shared__ int h[NCB];
    for (int i = threadIdx.x; i < NCB; i += 256) h[i] = 0;
    __syncthreads();
    int stride = gridDim.x * 256;
    for (int i = blockIdx.x * 256 + threadIdx.x; i < NM / 4; i += stride) {
        float4 v = S4[i];
        if (v.x > -2.0f) atomicAdd(&h[bin_c(v.x)], 1);
        if (v.y > -2.0f) atomicAdd(&h[bin_c(v.y)], 1);
        if (v.z > -2.0f) atomicAdd(&h[bin_c(v.z)], 1);
        if (v.w > -2.0f) atomicAdd(&h[bin_c(v.w)], 1);
    }
    __syncthreads();
    for (int i = threadIdx.x; i < NCB; i += 256)
        if (h[i]) atomicAdd(&hist[i], h[i]);
}

// ---- 9. find cutoff bin b*, then G1 = count(bin >= b*+11) ----
__global__ __launch_bounds__(256) void k_findcut(const int* __restrict__ hist, int* __restrict__ scl) {
    __shared__ int part[256];
    __shared__ int sb;
    int t = threadIdx.x;
    int loc[8]; int s = 0;
    for (int j = 0; j < 8; ++j) { loc[j] = hist[t * 8 + j]; s += loc[j]; }
    part[t] = s;
    __syncthreads();
    if (t == 0) { int acc = 0; for (int i = 255; i >= 0; --i) { int v = part[i]; part[i] = acc; acc += v; } }
    __syncthreads();
    int run = part[t];
    for (int j = 7; j >= 0; --j) {
        int h = loc[j];
        run += h;
        if (run >= NUM_ADD && run - h < NUM_ADD) { scl[0] = t * 8 + j; sb = t * 8 + j; }
    }
    __syncthreads();
    int bstar = sb;
    int g = 0;
    for (int i = bstar + 11 + t; i < NCB; i += 256) g += hist[i];
    part[t] = g;
    __syncthreads();
    for (int st2 = 128; st2 > 0; st2 >>= 1) { if (t < st2) part[t] += part[t + st2]; __syncthreads(); }
    if (t == 0) scl[1] = part[0];    // G1: certainly-selected (exact integer count)
}

// ---- 10. collect via two-level compaction: LDS buffers, 1 global atomic/block/flush ----
// (fixes the 408us same-address-atomic serialization: ~130K global RMW -> ~2K)
#define LB1 4096
#define LB2 2048
__global__ __launch_bounds__(256) void k_collect(const float4* __restrict__ S4,
        int* __restrict__ scl, int* __restrict__ cidx, int* __restrict__ cidx2) {
    __shared__ int buf1[LB1];
    __shared__ int buf2[LB2];
    __shared__ int c1, c2, g1, g2;
    int t = threadIdx.x;
    if (t == 0) { c1 = 0; c2 = 0; }
    __syncthreads();
    int bstar = scl[0];
    const int total4 = NM / 4;
    for (int i0 = blockIdx.x * 256; i0 < total4; i0 += gridDim.x * 256) {
        // flush if next iteration (<=1024 adds per list) might overflow
        if (c1 > LB1 - 1024 || c2 > LB2 - 1024) {
            if (t == 0) { g1 = atomicAdd(&scl[2], c1); g2 = atomicAdd(&scl[3], c2); }
            __syncthreads();
            for (int j = t; j < c1; j += 256) { int g = g1 + j; if (g < CAP)  cidx[g]  = buf1[j]; }
            for (int j = t; j < c2; j += 256) { int g = g2 + j; if (g < CAP2) cidx2[g] = buf2[j]; }
            __syncthreads();
            if (t == 0) { c1 = 0; c2 = 0; }
            __syncthreads();
        }
        int i = i0 + t;
        if (i < total4) {
            float4 v = S4[i];
            float sc;
            #define COLLECT1(comp, cc)                                         \
                sc = comp;                                                     \
                if (sc > -2.0f) {                                              \
                    int b = bin_c(sc);                                         \
                    if (b >= bstar + 11) {                                     \
                        int s2 = atomicAdd(&c2, 1);                            \
                        buf2[s2] = i * 4 + cc;                                 \
                    } else if (b >= bstar - 11) {                              \
                        int s1 = atomicAdd(&c1, 1);                            \
                        buf1[s1] = i * 4 + cc;                                 \
                    }                                                          \
                }
            COLLECT1(v.x, 0) COLLECT1(v.y, 1) COLLECT1(v.z, 2) COLLECT1(v.w, 3)
            #undef COLLECT1
        }
        __syncthreads();   // LDS counters stable before next-iter flush check
    }
    if (t == 0) { g1 = atomicAdd(&scl[2], c1); g2 = atomicAdd(&scl[3], c2); }
    __syncthreads();
    for (int j = t; j < c1; j += 256) { int g = g1 + j; if (g < CAP)  cidx[g]  = buf1[j]; }
    for (int j = t; j < c2; j += 256) { int g = g2 + j; if (g < CAP2) cidx2[g] = buf2[j]; }
}

// ---- 11. pure-stream output: out = H * st_mask  (no S, no atomics) ----
__global__ __launch_bounds__(256) void k_out(const float4* __restrict__ H4,
        const float4* __restrict__ p4, const float4* __restrict__ e4,
        float4* __restrict__ o4) {
    size_t i = (size_t)blockIdx.x * 256 + threadIdx.x;
    float4 h = H4[i];
    float4 p = p4[i];
    float4 e = e4[i];
    float4 o;
    o.x = h.x * st_mask(p.x, e.x);
    o.y = h.y * st_mask(p.y, e.y);
    o.z = h.z * st_mask(p.z, e.z);
    o.w = h.w * st_mask(p.w, e.w);
    o4[i] = o;
}

// ---- 12. scatter-write certain entries: out = (H+1)*mask ----
__global__ __launch_bounds__(256) void k_selc(const int* __restrict__ scl,
        const int* __restrict__ cidx2, const float* __restrict__ H,
        const float* __restrict__ prob, const float* __restrict__ eps,
        float* __restrict__ out) {
    int n = scl[3]; if (n > CAP2) n = CAP2;
    for (int i = blockIdx.x * 256 + threadIdx.x; i < n; i += 256 * 128) {
        int idx = cidx2[i];
        out[idx] = (H[idx] + 1.0f) * st_mask(prob[idx], eps[idx]);
    }
}

// ---- 13. exact fp64 values for band candidates ----
__global__ __launch_bounds__(256) void k_exact(
        const int* __restrict__ scl, const int* __restrict__ cidx, double* __restrict__ cval,
        const float* __restrict__ X, const double* __restrict__ eXd, const float* __restrict__ cw) {
    int nc = scl[2]; if (nc > CAP) nc = CAP;
    for (int i = blockIdx.x * 256 + threadIdx.x; i < nc; i += 256 * 512) {
        int idx = cidx[i];
        int n = idx >> 12, m = idx & (M_EDGES - 1);
        double acc = 0.0;
        for (int c = 0; c < NCH; ++c) {
            double dn = 0.0, de = 0.0, dt = 0.0;
            for (int d = 0; d < DIM; ++d) {
                double w  = (double)cw[c * DIM + d];
                double xn = (double)X[n * DIM + d] * w;
                double xe = eXd[m * DIM + d] * w;
                dn += xn * xn; de += xe * xe; dt += xn * xe;
            }
            acc += dt / (fmax(sqrt(dn), 1e-12) * fmax(sqrt(de), 1e-12));
        }
        cval[i] = acc * 0.25;
    }
}

// ---- 14. fine fp64 histogram of band values ----
__global__ __launch_bounds__(256) void k_fhist(const int* __restrict__ scl,
                                               const int* __restrict__ cidx,
                                               const double* __restrict__ cval,
                                               int* __restrict__ fh) {
    int nc = scl[2]; if (nc > CAP) nc = CAP;
    int bstar = scl[0];
    for (int i = blockIdx.x * 256 + threadIdx.x; i < nc; i += 256 * 256)
        atomicAdd(&fh[fbin_of(cval[i], bstar)], 1);
}

// ---- 15. find fine cutoff f* for target T = NUM_ADD - G1 ----
__global__ __launch_bounds__(1024) void k_ffind(const int* __restrict__ fh, int* __restrict__ scl) {
    __shared__ int part[1024];
    int T = NUM_ADD - scl[1];            // >= 1 by construction of b*
    int t = threadIdx.x;
    int loc[32]; int s = 0;
    for (int j = 0; j < 32; ++j) { loc[j] = fh[t * 32 + j]; s += loc[j]; }
    part[t] = s;
    __syncthreads();
    if (t == 0) { int acc = 0; for (int i = 1023; i >= 0; --i) { int v = part[i]; part[i] = acc; acc += v; } }
    __syncthreads();
    int run = part[t];
    for (int j = 31; j >= 0; --j) {
        int h = loc[j];
        run += h;
        if (run >= T && run - h < T) { scl[4] = t * 32 + j; scl[5] = run - h; }
    }
}

// ---- 16. write band candidates strictly above the fine cutoff bin ----
__global__ __launch_bounds__(256) void k_write(
        const int* __restrict__ scl, const int* __restrict__ cidx, const double* __restrict__ cval,
        const float* __restrict__ H, const float* __restrict__ prob, const float* __restrict__ eps,
        float* __restrict__ out) {
    int nc = scl[2]; if (nc > CAP) nc = CAP;
    int fs = scl[4], bstar = scl[0];
    for (int i = blockIdx.x * 256 + threadIdx.x; i < nc; i += 256 * 256) {
        if (fbin_of(cval[i], bstar) > fs) {
            int idx = cidx[i];
            out[idx] = (H[idx] + 1.0f) * st_mask(prob[idx], eps[idx]);
        }
    }
}

// ---- 17. exact tie-break inside the single ambiguous fine bin ----
__global__ __launch_bounds__(256) void k_tie(
        const int* __restrict__ scl, const int* __restrict__ cidx, const double* __restrict__ cval,
        const float* __restrict__ H, const float* __restrict__ prob, const float* __restrict__ eps,
        float* __restrict__ out) {
    __shared__ double mv[256];
    __shared__ int    mi[256];
    __shared__ int    cnt;
    int nc = scl[2]; if (nc > CAP) nc = CAP;
    int T = NUM_ADD - scl[1];
    int fs = scl[4], G1f = scl[5], bstar = scl[0];
    int t = threadIdx.x;
    if (t == 0) cnt = 0;
    __syncthreads();
    for (int i = t; i < nc; i += 256) {
        if (fbin_of(cval[i], bstar) == fs) {
            int s = atomicAdd(&cnt, 1);
            if (s < 256) { mv[s] = cval[i]; mi[s] = cidx[i]; }
        }
    }
    __syncthreads();
    int nm = min(cnt, 256);
    for (int k = t; k < nm; k += 256) {
        double v = mv[k]; int idx = mi[k];
        int rank = G1f;
        for (int j = 0; j < nm; ++j)
            rank += (mv[j] > v || (mv[j] == v && mi[j] < idx)) ? 1 : 0;
        if (rank < T)
            out[idx] = (H[idx] + 1.0f) * st_mask(prob[idx], eps[idx]);
    }
}

extern "C" void kernel_launch(void* const* d_in, const int* in_sizes, int n_in,
                              void* d_out, int out_size, void* d_ws, size_t ws_size,
                              hipStream_t stream) {
    const float* X    = (const float*)d_in[0];
    const float* H    = (const float*)d_in[1];
    const int*   Vv   = (const int*)d_in[2];
    const int*   E    = (const int*)d_in[3];
    const float* prob = (const float*)d_in[4];
    const float* cw   = (const float*)d_in[5];
    const float* eps  = (const float*)d_in[6];
    float* out = (float*)d_out;
    char*  ws  = (char*)d_ws;

    double*         eXd   = (double*)(ws + EXD_OFF);
    unsigned short* Afc   = (unsigned short*)(ws + AFC_OFF);
    unsigned short* Bfc   = (unsigned short*)(ws + BFC_OFF);
    int*            bkt   = (int*)(ws + BKT_OFF);
    double*         cval  = (double*)(ws + CVAL_OFF);
    int*            cidx  = (int*)(ws + CIDX_OFF);
    int*            cidx2 = (int*)(ws + CIDX2_OFF);
    int*            cnt   = (int*)(ws + CNT_OFF);
    int*            offs  = (int*)(ws + OFFS_OFF);
    int*            cur   = (int*)(ws + CUR_OFF);
    int*            hist  = (int*)(ws + HIST_OFF);
    int*            fh    = (int*)(ws + FHIST_OFF);
    int*            scl   = (int*)(ws + SCL_OFF);

    hipMemsetAsync(ws + CNT_OFF, 0, (size_t)ZERO_BYTES, stream);

    k_count<<<NNZ_K / 256, 256, 0, stream>>>(E, cnt);
    k_scan<<<1, 256, 0, stream>>>(cnt, offs);
    k_fill<<<NNZ_K / 256, 256, 0, stream>>>(E, offs, cur, bkt);
    k_edge_mean<<<M_EDGES, 128, 0, stream>>>(Vv, cnt, offs, bkt, X, eXd);
    k_fc<float><<<N_NODES, 128, 0, stream>>>(X, cw, Afc);
    k_fc<double><<<M_EDGES, 128, 0, stream>>>(eXd, cw, Bfc);
    dim3 gg(M_EDGES / 128, N_NODES / 128);
    k_gemm_mfma<<<gg, 256, 0, stream>>>(Afc, Bfc, out);
    k_mask<<<NNZ_K / 256, 256, 0, stream>>>(Vv, E, out);
    k_hist_coarse<<<1024, 256, 0, stream>>>((const float4*)out, hist);
    k_findcut<<<1, 256, 0, stream>>>(hist, scl);
    k_collect<<<1024, 256, 0, stream>>>((const float4*)out, scl, cidx, cidx2);
    k_out<<<NM / 4 / 256, 256, 0, stream>>>((const float4*)H, (const float4*)prob,
                                            (const float4*)eps, (float4*)out);
    k_selc<<<128, 256, 0, stream>>>(scl, cidx2, H, prob, eps, out);
    k_exact<<<512, 256, 0, stream>>>(scl, cidx, cval, X, eXd, cw);
    k_fhist<<<256, 256, 0, stream>>>(scl, cidx, cval, fh);
    k_ffind<<<1, 1024, 0, stream>>>(fh, scl);
    k_write<<<256, 256, 0, stream>>>(scl, cidx, cval, H, prob, eps, out);
    k_tie<<<1, 256, 0, stream>>>(scl, cidx, cval, H, prob, eps, out);
}